// Round 7
// baseline (651.812 us; speedup 1.0000x reference)
//
#include <hip/hip_runtime.h>

#define N_NODES 100000
#define N_EDGES 1600000

typedef __attribute__((ext_vector_type(8))) short bf16x8;
typedef __attribute__((ext_vector_type(4))) float f32x4;
typedef __attribute__((ext_vector_type(2))) float f32x2;
typedef __attribute__((ext_vector_type(4))) unsigned short u16x4;

__device__ __forceinline__ float b2f(unsigned short u) {
    union { unsigned int i; float f; } v; v.i = ((unsigned int)u) << 16; return v.f;
}
__device__ __forceinline__ unsigned short f2b(float f) {
    union { float ff; unsigned int i; } v; v.ff = f;
    unsigned int x = v.i;
    x += 0x7fffu + ((x >> 16) & 1u);   // round-to-nearest-even
    return (unsigned short)(x >> 16);
}
__device__ __forceinline__ float rdlanef(float v, int l) {
    return __uint_as_float(__builtin_amdgcn_readlane(__float_as_uint(v), l));
}

// ---------------- f32 -> bf16 cast of x ----------------
__global__ __launch_bounds__(256) void k_cast4(const float* __restrict__ in,
                                               unsigned short* __restrict__ out, int n4) {
    int i = blockIdx.x * 256 + threadIdx.x;
    if (i < n4) {
        f32x4 v = *(const f32x4*)&in[(size_t)i * 4];
        u16x4 o;
        o[0] = f2b(v[0]); o[1] = f2b(v[1]); o[2] = f2b(v[2]); o[3] = f2b(v[3]);
        *(u16x4*)&out[(size_t)i * 4] = o;
    }
}

// cast + TRANSPOSE all 4 weight matrices -> Wt[col][k] bf16, contiguous pW|W1|W2|W3
__global__ __launch_bounds__(256) void k_castWT(
    const float* __restrict__ pW, const float* __restrict__ W1,
    const float* __restrict__ W2, const float* __restrict__ W3,
    unsigned short* __restrict__ out)
{
    int i = blockIdx.x * 256 + threadIdx.x;   // flat output index, 114688 total
    if (i >= 114688) return;
    const float* src; int K, base;
    if (i < 16384)      { src = pW; K = 128; base = 0; }
    else if (i < 32768) { src = W1; K = 128; base = 16384; }
    else if (i < 65536) { src = W2; K = 256; base = 32768; }
    else                { src = W3; K = 384; base = 65536; }
    int loc = i - base;
    int col = loc / K, k = loc - col * K;
    out[i] = f2b(src[(size_t)k * 128 + col]);
}

// ---------------- graph build ----------------
#define SCAT_GROUPS 8
#define SCAT_WIN ((N_NODES + SCAT_GROUPS - 1) / SCAT_GROUPS)    // 12500
#define BUCKET_CAP 204800                                       // >= E/8 + 5 sigma
#define PART_BLOCKS 256
#define EPB (N_EDGES / PART_BLOCKS)                             // 6250

__global__ void k_init_deg(int* deg, int* gcur) {
    int i = blockIdx.x * 256 + threadIdx.x;
    if (i < N_NODES) deg[i] = 1;   // self-loop
    if (i < SCAT_GROUPS) gcur[i] = i * BUCKET_CAP;
}

// partition edges into 8 dst-window buckets (coalesced writes) + fused degree hist
__global__ __launch_bounds__(256) void k_part(
    const int* __restrict__ src, const int* __restrict__ dst,
    int* __restrict__ deg, int* __restrict__ gcur,
    unsigned long long* __restrict__ part)
{
    __shared__ unsigned long long eb[EPB];   // 50 KB staging
    __shared__ int bcnt[8];
    __shared__ int lcur[8];
    const int tid = threadIdx.x;
    const int ll  = tid & 63;
    const int base = blockIdx.x * EPB;
    if (tid < 8) bcnt[tid] = 0;
    __syncthreads();

    // phase 1: load to LDS + global degree hist + per-bucket counts
    int mycnt[8] = {0, 0, 0, 0, 0, 0, 0, 0};
    for (int i = tid; i < EPB; i += 256) {
        int s = src[base + i];
        int d = dst[base + i];
        eb[i] = ((unsigned long long)(unsigned)d << 32) | (unsigned)s;
        atomicAdd(&deg[d], 1);
        int b = d / SCAT_WIN;
#pragma unroll
        for (int bk = 0; bk < 8; ++bk) mycnt[bk] += (b == bk);
    }
#pragma unroll
    for (int bk = 0; bk < 8; ++bk) {
        int c = mycnt[bk];
        for (int o = 1; o < 64; o <<= 1) c += __shfl_xor(c, o, 64);
        if (ll == 0) atomicAdd(&bcnt[bk], c);
    }
    __syncthreads();
    if (tid < 8) lcur[tid] = atomicAdd(&gcur[tid], bcnt[tid]);
    __syncthreads();

    // phase 2: ballot-ordered coalesced write-out
    for (int ib = 0; ib < EPB; ib += 256) {
        int i = ib + tid;
        bool valid = i < EPB;
        unsigned long long e = valid ? eb[i] : 0ULL;
        int b = valid ? (int)(e >> 32) / SCAT_WIN : -1;
        unsigned long long masks[8]; int cnts[8];
#pragma unroll
        for (int bk = 0; bk < 8; ++bk) {
            masks[bk] = __ballot(b == bk);
            cnts[bk] = __popcll(masks[bk]);
        }
        int posv = 0;
        if (ll < 8) posv = atomicAdd(&lcur[ll], cnts[ll]);
        int myoff = 0;
#pragma unroll
        for (int bk = 0; bk < 8; ++bk) {
            int bb = __builtin_amdgcn_readlane(posv, bk);
            if (b == bk) myoff = bb + __popcll(masks[bk] & ((1ULL << ll) - 1ULL));
        }
        if (valid) part[myoff] = e;
    }
}

#define SCAN_CHUNK 2048
#define SCAN_BLOCKS ((N_NODES + SCAN_CHUNK - 1) / SCAN_CHUNK)   // 49

__global__ __launch_bounds__(256) void k_deg_part(const int* __restrict__ deg,
                                                  int* __restrict__ psum) {
    int b = blockIdx.x, t = threadIdx.x;
    int base = b * SCAN_CHUNK + t * 8;
    int s = 0;
#pragma unroll
    for (int i = 0; i < 8; ++i) { int idx = base + i; if (idx < N_NODES) s += deg[idx]; }
    for (int o = 1; o < 64; o <<= 1) s += __shfl_xor(s, o, 64);
    __shared__ int ws[4];
    if ((t & 63) == 0) ws[t >> 6] = s;
    __syncthreads();
    if (t == 0) psum[b] = ws[0] + ws[1] + ws[2] + ws[3];
}

__global__ void k_scan_off(const int* __restrict__ psum, int* __restrict__ poff) {
    int t = threadIdx.x;          // 64 threads
    int v = (t < SCAN_BLOCKS) ? psum[t] : 0;
    int sc = v;
    for (int o = 1; o < 64; o <<= 1) { int u = __shfl_up(sc, o, 64); if (t >= o) sc += u; }
    if (t < SCAN_BLOCKS) poff[t] = sc - v;
}

__global__ __launch_bounds__(256) void k_scan_final(
    const int* __restrict__ deg, const int* __restrict__ poff,
    int* __restrict__ row_ptr, int* __restrict__ cursor, float* __restrict__ dinv)
{
    int b = blockIdx.x, t = threadIdx.x;
    int base = b * SCAN_CHUNK + t * 8;
    int v[8]; int s = 0;
#pragma unroll
    for (int i = 0; i < 8; ++i) { int idx = base + i; v[i] = (idx < N_NODES) ? deg[idx] : 0; s += v[i]; }
    int lane = t & 63, wv = t >> 6;
    int sc = s;
    for (int o = 1; o < 64; o <<= 1) { int u = __shfl_up(sc, o, 64); if (lane >= o) sc += u; }
    __shared__ int wsum[4];
    if (lane == 63) wsum[wv] = sc;
    __syncthreads();
    int woff = 0;
    for (int i = 0; i < wv; ++i) woff += wsum[i];
    int excl = poff[b] + woff + sc - s;
#pragma unroll
    for (int i = 0; i < 8; ++i) {
        int idx = base + i;
        if (idx < N_NODES) {
            row_ptr[idx] = excl; cursor[idx] = excl;
            dinv[idx] = rsqrtf((float)v[i]);
            excl += v[i];
        }
    }
}

// windowed scatter from the partitioned buckets: group w reads ONLY bucket w
#define SCAT_BLOCKS 2048

__global__ __launch_bounds__(256) void k_scat2(
    const unsigned long long* __restrict__ part, const int* __restrict__ gcur,
    int* __restrict__ cursor, int* __restrict__ ssrc)
{
    const int w  = blockIdx.x & (SCAT_GROUPS - 1);
    const int g  = blockIdx.x >> 3;                 // 0..255 within group
    const int b0 = w * BUCKET_CAP;
    const int cnt = gcur[w] - b0;
    const int stride = (SCAT_BLOCKS / SCAT_GROUPS) * 256;   // 65536
    for (int i = g * 256 + threadIdx.x; i < cnt; i += stride) {
        unsigned long long e = part[b0 + i];
        int d = (int)(e >> 32);
        int s = (int)(e & 0xffffffffu);
        int p = atomicAdd(&cursor[d], 1);
        ssrc[p] = s;
    }
}

// ---------------- GEMM: out[n,128] = relu?( concat(A0..A_{NC-1}) @ W + bias? ) ----------------
template<int NC, bool RELU, bool BIAS>
__global__ __launch_bounds__(256) void k_gemm(
    const unsigned short* __restrict__ A0, const unsigned short* __restrict__ A1,
    const unsigned short* __restrict__ A2, const unsigned short* __restrict__ WtG,
    const float* __restrict__ bias, unsigned short* __restrict__ out)
{
    const int tid  = threadIdx.x;
    const int wave = tid >> 6, lane = tid & 63;
    const int l15 = lane & 15, lg = lane >> 4;
    const int K = NC * 128;
    const int rbase = blockIdx.x * 128 + wave * 32;

    f32x4 acc[2][8];
#pragma unroll
    for (int i = 0; i < 2; ++i)
#pragma unroll
        for (int j = 0; j < 8; ++j) acc[i][j] = (f32x4)(0.0f);

    int ar0 = rbase + l15;      if (ar0 >= N_NODES) ar0 = N_NODES - 1;
    int ar1 = rbase + 16 + l15; if (ar1 >= N_NODES) ar1 = N_NODES - 1;

    for (int c = 0; c < NC; ++c) {
        const unsigned short* Ac = (c == 0) ? A0 : ((c == 1) ? A1 : A2);
#pragma unroll
        for (int ks = 0; ks < 4; ++ks) {
            const int ko = ks * 32 + lg * 8;
            bf16x8 a0 = *(const bf16x8*)&Ac[(size_t)ar0 * 128 + ko];
            bf16x8 a1 = *(const bf16x8*)&Ac[(size_t)ar1 * 128 + ko];
#pragma unroll
            for (int cf = 0; cf < 8; ++cf) {
                bf16x8 b = *(const bf16x8*)&WtG[(size_t)(cf * 16 + l15) * K + c * 128 + ko];
                acc[0][cf] = __builtin_amdgcn_mfma_f32_16x16x32_bf16(a0, b, acc[0][cf], 0, 0, 0);
                acc[1][cf] = __builtin_amdgcn_mfma_f32_16x16x32_bf16(a1, b, acc[1][cf], 0, 0, 0);
            }
        }
    }
#pragma unroll
    for (int ai = 0; ai < 2; ++ai) {
#pragma unroll
        for (int cf = 0; cf < 8; ++cf) {
            int col = cf * 16 + l15;
            float bv = BIAS ? bias[col] : 0.0f;
#pragma unroll
            for (int j = 0; j < 4; ++j) {
                int row = rbase + ai * 16 + lg * 4 + j;
                if (row < N_NODES) {
                    float v = acc[ai][cf][j] + bv;
                    if (RELU) v = fmaxf(v, 0.0f);
                    out[(size_t)row * 128 + col] = f2b(v);
                }
            }
        }
    }
}

// ---------------- aggregation: out = relu(dinv_i * sum(dinv_s * t_s) + dinv_i^2 * t_i + b) ----
template<bool FINAL>
__global__ __launch_bounds__(256) void k_agg(
    const unsigned short* __restrict__ t, const int* __restrict__ ssrc,
    const int* __restrict__ row_ptr, const int* __restrict__ deg,
    const float* __restrict__ dinv, const float* __restrict__ bias,
    void* __restrict__ out_v)
{
    const int wave = threadIdx.x >> 6;
    const int lane = threadIdx.x & 63;
    const int node = blockIdx.x * 4 + wave;
    if (node >= N_NODES) return;

    const int beg = row_ptr[node];
    const int cnt = deg[node] - 1;
    float a0 = 0.0f, a1 = 0.0f;

    for (int kb = 0; kb < cnt; kb += 64) {
        const int rem = cnt - kb;
        const int lim = rem < 64 ? rem : 64;
        int sk = 0;
        if (lane < lim) sk = ssrc[beg + kb + lane];
        float wk = dinv[sk];

        int k = 0;
        for (; k + 8 <= lim; k += 8) {
            unsigned int p[8];
            float w[8];
#pragma unroll
            for (int u = 0; u < 8; ++u) {
                int s = __builtin_amdgcn_readlane(sk, k + u);
                p[u] = *(const unsigned int*)&t[(size_t)s * 128 + lane * 2];
                w[u] = rdlanef(wk, k + u);
            }
#pragma unroll
            for (int u = 0; u < 8; ++u) {
                a0 = fmaf(w[u], b2f((unsigned short)(p[u] & 0xffffu)), a0);
                a1 = fmaf(w[u], b2f((unsigned short)(p[u] >> 16)), a1);
            }
        }
        for (; k < lim; ++k) {
            int s0 = __builtin_amdgcn_readlane(sk, k);
            float w0 = rdlanef(wk, k);
            unsigned int p0 = *(const unsigned int*)&t[(size_t)s0 * 128 + lane * 2];
            a0 = fmaf(w0, b2f((unsigned short)(p0 & 0xffffu)), a0);
            a1 = fmaf(w0, b2f((unsigned short)(p0 >> 16)), a1);
        }
    }

    float di = dinv[node];
    unsigned int ps = *(const unsigned int*)&t[(size_t)node * 128 + lane * 2];
    float s0 = b2f((unsigned short)(ps & 0xffffu));
    float s1 = b2f((unsigned short)(ps >> 16));
    f32x2 bv = *(const f32x2*)&bias[lane * 2];
    float o0 = fmaxf(di * a0 + di * di * s0 + bv[0], 0.0f);
    float o1 = fmaxf(di * a1 + di * di * s1 + bv[1], 0.0f);
    if (FINAL) {
        f32x2 po; po[0] = o0; po[1] = o1;
        *(f32x2*)((float*)out_v + (size_t)node * 128 + lane * 2) = po;
    } else {
        unsigned short* out = (unsigned short*)out_v;
        unsigned int po = (unsigned int)f2b(o0) | ((unsigned int)f2b(o1) << 16);
        *(unsigned int*)&out[(size_t)node * 128 + lane * 2] = po;
    }
}

// ---------------- launch ----------------
extern "C" void kernel_launch(void* const* d_in, const int* in_sizes, int n_in,
                              void* d_out, int out_size, void* d_ws, size_t ws_size,
                              hipStream_t stream)
{
    const float* x  = (const float*)d_in[0];
    const int*   ei = (const int*)d_in[1];
    const float* pW = (const float*)d_in[2];
    const float* pb = (const float*)d_in[3];
    const float* W1 = (const float*)d_in[4];
    const float* b1 = (const float*)d_in[5];
    const float* W2 = (const float*)d_in[6];
    const float* b2 = (const float*)d_in[7];
    const float* W3 = (const float*)d_in[8];
    const float* b3 = (const float*)d_in[9];
    const int* src = ei;
    const int* dst = ei + N_EDGES;

    char* ws = (char*)d_ws;
    size_t off = 0;
    auto alloc = [&](size_t bytes) -> char* {
        char* p = ws + off; off += (bytes + 255) & ~(size_t)255; return p;
    };
    const size_t NB = (size_t)N_NODES * 128;
    unsigned short* xb = (unsigned short*)alloc(NB * 2);
    unsigned short* xp = (unsigned short*)alloc(NB * 2);
    unsigned short* h1 = (unsigned short*)alloc(NB * 2);
    unsigned short* h2 = (unsigned short*)alloc(NB * 2);
    unsigned short* tb = (unsigned short*)alloc(NB * 2);   // GEMM temp; aliased as `part` during graph build
    unsigned short* Wb = (unsigned short*)alloc((size_t)114688 * 2);   // W^T bf16
    int*   deg  = (int*)alloc((size_t)N_NODES * 4);
    int*   rp   = (int*)alloc((size_t)N_NODES * 4);
    int*   cur  = (int*)alloc((size_t)N_NODES * 4);
    float* dinv = (float*)alloc((size_t)N_NODES * 4);
    int*   psum = (int*)alloc((size_t)SCAN_BLOCKS * 4);
    int*   poff = (int*)alloc((size_t)SCAN_BLOCKS * 4);
    int*   gcur = (int*)alloc((size_t)SCAT_GROUPS * 4);
    int*   ssrc = (int*)alloc((size_t)(N_EDGES + N_NODES) * 4);

    // bucket-partitioned edges (13.1 MB) alias over tb (25.6 MB): tb is first
    // written by k_gemm AFTER k_scat2 has consumed part. Same stream -> safe.
    unsigned long long* part = (unsigned long long*)tb;

    unsigned short* pWt = Wb;
    unsigned short* W1t = Wb + 16384;
    unsigned short* W2t = Wb + 32768;
    unsigned short* W3t = Wb + 65536;

    // casts
    k_cast4<<<(int)(NB / 4 + 255) / 256, 256, 0, stream>>>(x, xb, (int)(NB / 4));
    k_castWT<<<(114688 + 255) / 256, 256, 0, stream>>>(pW, W1, W2, W3, Wb);

    // graph build
    k_init_deg<<<(N_NODES + 255) / 256, 256, 0, stream>>>(deg, gcur);
    k_part<<<PART_BLOCKS, 256, 0, stream>>>(src, dst, deg, gcur, part);
    k_deg_part<<<SCAN_BLOCKS, 256, 0, stream>>>(deg, psum);
    k_scan_off<<<1, 64, 0, stream>>>(psum, poff);
    k_scan_final<<<SCAN_BLOCKS, 256, 0, stream>>>(deg, poff, rp, cur, dinv);
    k_scat2<<<SCAT_BLOCKS, 256, 0, stream>>>(part, gcur, cur, ssrc);

    const int gblocks = (N_NODES + 127) / 128;
    const int ablocks = (N_NODES + 3) / 4;

    k_gemm<1, true, true><<<gblocks, 256, 0, stream>>>(xb, nullptr, nullptr, pWt, pb, xp);
    k_gemm<1, false, false><<<gblocks, 256, 0, stream>>>(xb, nullptr, nullptr, W1t, nullptr, tb);
    k_agg<false><<<ablocks, 256, 0, stream>>>(tb, ssrc, rp, deg, dinv, b1, h1);
    k_gemm<2, false, false><<<gblocks, 256, 0, stream>>>(xp, h1, nullptr, W2t, nullptr, tb);
    k_agg<false><<<ablocks, 256, 0, stream>>>(tb, ssrc, rp, deg, dinv, b2, h2);
    k_gemm<3, false, false><<<gblocks, 256, 0, stream>>>(xp, h1, h2, W3t, nullptr, tb);
    k_agg<true><<<ablocks, 256, 0, stream>>>(tb, ssrc, rp, deg, dinv, b3, d_out);
}

// Round 8
// 649.158 us; speedup vs baseline: 1.0041x; 1.0041x over previous
//
#include <hip/hip_runtime.h>

#define N_NODES 100000
#define N_EDGES 1600000

typedef __attribute__((ext_vector_type(8))) short bf16x8;
typedef __attribute__((ext_vector_type(4))) float f32x4;
typedef __attribute__((ext_vector_type(2))) float f32x2;
typedef __attribute__((ext_vector_type(4))) unsigned short u16x4;

__device__ __forceinline__ float b2f(unsigned short u) {
    union { unsigned int i; float f; } v; v.i = ((unsigned int)u) << 16; return v.f;
}
__device__ __forceinline__ unsigned short f2b(float f) {
    union { float ff; unsigned int i; } v; v.ff = f;
    unsigned int x = v.i;
    x += 0x7fffu + ((x >> 16) & 1u);   // round-to-nearest-even
    return (unsigned short)(x >> 16);
}

// ---------------- f32 -> bf16 cast of x ----------------
__global__ __launch_bounds__(256) void k_cast4(const float* __restrict__ in,
                                               unsigned short* __restrict__ out, int n4) {
    int i = blockIdx.x * 256 + threadIdx.x;
    if (i < n4) {
        f32x4 v = *(const f32x4*)&in[(size_t)i * 4];
        u16x4 o;
        o[0] = f2b(v[0]); o[1] = f2b(v[1]); o[2] = f2b(v[2]); o[3] = f2b(v[3]);
        *(u16x4*)&out[(size_t)i * 4] = o;
    }
}

// cast + TRANSPOSE all 4 weight matrices -> Wt[col][k] bf16, contiguous pW|W1|W2|W3
__global__ __launch_bounds__(256) void k_castWT(
    const float* __restrict__ pW, const float* __restrict__ W1,
    const float* __restrict__ W2, const float* __restrict__ W3,
    unsigned short* __restrict__ out)
{
    int i = blockIdx.x * 256 + threadIdx.x;   // flat output index, 114688 total
    if (i >= 114688) return;
    const float* src; int K, base;
    if (i < 16384)      { src = pW; K = 128; base = 0; }
    else if (i < 32768) { src = W1; K = 128; base = 16384; }
    else if (i < 65536) { src = W2; K = 256; base = 32768; }
    else                { src = W3; K = 384; base = 65536; }
    int loc = i - base;
    int col = loc / K, k = loc - col * K;
    out[i] = f2b(src[(size_t)k * 128 + col]);
}

// ---------------- graph build ----------------
#define SCAT_GROUPS 8
#define SCAT_WIN ((N_NODES + SCAT_GROUPS - 1) / SCAT_GROUPS)    // 12500
#define BUCKET_CAP 204800
#define PART_BLOCKS 782
#define PART_EPB 2048
#define HIST_BLOCKS 2048
#define SCAT_BLOCKS 2048

__global__ void k_init_deg(int* deg, int* gcur) {
    int i = blockIdx.x * 256 + threadIdx.x;
    if (i < N_NODES) deg[i] = 1;   // self-loop
    if (i < SCAT_GROUPS) gcur[i] = i * BUCKET_CAP;
}

// register-only edge partition into 8 dst-window buckets (coalesced writes, no hist)
__global__ __launch_bounds__(256) void k_part(
    const int* __restrict__ src, const int* __restrict__ dst,
    int* __restrict__ gcur, unsigned long long* __restrict__ part)
{
    __shared__ int bcnt[8];
    __shared__ int lcur[8];
    const int tid = threadIdx.x;
    const int ll  = tid & 63;
    const int base = blockIdx.x * PART_EPB;
    int sv[8], dv[8], bv[8];
    int mycnt[8] = {0, 0, 0, 0, 0, 0, 0, 0};
#pragma unroll
    for (int u = 0; u < 8; ++u) {
        int e = base + u * 256 + tid;
        bool val = e < N_EDGES;
        sv[u] = val ? src[e] : 0;
        dv[u] = val ? dst[e] : 0;
        bv[u] = val ? dv[u] / SCAT_WIN : -1;
#pragma unroll
        for (int bk = 0; bk < 8; ++bk) mycnt[bk] += (bv[u] == bk);
    }
    if (tid < 8) bcnt[tid] = 0;
    __syncthreads();
#pragma unroll
    for (int bk = 0; bk < 8; ++bk) {
        int c = mycnt[bk];
        for (int o = 1; o < 64; o <<= 1) c += __shfl_xor(c, o, 64);
        if (ll == 0 && c) atomicAdd(&bcnt[bk], c);
    }
    __syncthreads();
    if (tid < 8) lcur[tid] = atomicAdd(&gcur[tid], bcnt[tid]);
    __syncthreads();
#pragma unroll
    for (int u = 0; u < 8; ++u) {
        unsigned long long masks[8]; int cnts[8];
#pragma unroll
        for (int bk = 0; bk < 8; ++bk) {
            masks[bk] = __ballot(bv[u] == bk);
            cnts[bk]  = __popcll(masks[bk]);
        }
        int posv = 0;
        if (ll < 8) posv = atomicAdd(&lcur[ll], cnts[ll]);
        int myoff = 0;
#pragma unroll
        for (int bk = 0; bk < 8; ++bk) {
            int bb = __builtin_amdgcn_readlane(posv, bk);
            if (bv[u] == bk) myoff = bb + __popcll(masks[bk] & ((1ULL << ll) - 1ULL));
        }
        if (bv[u] >= 0)
            part[myoff] = ((unsigned long long)(unsigned)dv[u] << 32) | (unsigned)sv[u];
    }
}

// windowed degree hist from buckets: group w's atomics stay in its XCD's L2
__global__ __launch_bounds__(256) void k_hist2(
    const unsigned long long* __restrict__ part, const int* __restrict__ gcur,
    int* __restrict__ deg)
{
    const int w  = blockIdx.x & (SCAT_GROUPS - 1);
    const int g  = blockIdx.x >> 3;
    const int b0 = w * BUCKET_CAP;
    const int cnt = gcur[w] - b0;
    const int stride = (HIST_BLOCKS / SCAT_GROUPS) * 256;
    for (int i = g * 256 + threadIdx.x; i < cnt; i += stride) {
        int d = (int)(part[b0 + i] >> 32);
        atomicAdd(&deg[d], 1);
    }
}

#define SCAN_CHUNK 2048
#define SCAN_BLOCKS ((N_NODES + SCAN_CHUNK - 1) / SCAN_CHUNK)   // 49

__global__ __launch_bounds__(256) void k_deg_part(const int* __restrict__ deg,
                                                  int* __restrict__ psum) {
    int b = blockIdx.x, t = threadIdx.x;
    int base = b * SCAN_CHUNK + t * 8;
    int s = 0;
#pragma unroll
    for (int i = 0; i < 8; ++i) { int idx = base + i; if (idx < N_NODES) s += deg[idx]; }
    for (int o = 1; o < 64; o <<= 1) s += __shfl_xor(s, o, 64);
    __shared__ int ws[4];
    if ((t & 63) == 0) ws[t >> 6] = s;
    __syncthreads();
    if (t == 0) psum[b] = ws[0] + ws[1] + ws[2] + ws[3];
}

__global__ void k_scan_off(const int* __restrict__ psum, int* __restrict__ poff) {
    int t = threadIdx.x;          // 64 threads
    int v = (t < SCAN_BLOCKS) ? psum[t] : 0;
    int sc = v;
    for (int o = 1; o < 64; o <<= 1) { int u = __shfl_up(sc, o, 64); if (t >= o) sc += u; }
    if (t < SCAN_BLOCKS) poff[t] = sc - v;
}

__global__ __launch_bounds__(256) void k_scan_final(
    const int* __restrict__ deg, const int* __restrict__ poff,
    int* __restrict__ row_ptr, int* __restrict__ cursor, float* __restrict__ dinv)
{
    int b = blockIdx.x, t = threadIdx.x;
    int base = b * SCAN_CHUNK + t * 8;
    int v[8]; int s = 0;
#pragma unroll
    for (int i = 0; i < 8; ++i) { int idx = base + i; v[i] = (idx < N_NODES) ? deg[idx] : 0; s += v[i]; }
    int lane = t & 63, wv = t >> 6;
    int sc = s;
    for (int o = 1; o < 64; o <<= 1) { int u = __shfl_up(sc, o, 64); if (lane >= o) sc += u; }
    __shared__ int wsum[4];
    if (lane == 63) wsum[wv] = sc;
    __syncthreads();
    int woff = 0;
    for (int i = 0; i < wv; ++i) woff += wsum[i];
    int excl = poff[b] + woff + sc - s;
#pragma unroll
    for (int i = 0; i < 8; ++i) {
        int idx = base + i;
        if (idx < N_NODES) {
            row_ptr[idx] = excl; cursor[idx] = excl;
            dinv[idx] = rsqrtf((float)v[i]);
            excl += v[i];
        }
    }
}

// windowed scatter from the partitioned buckets: group w reads ONLY bucket w
__global__ __launch_bounds__(256) void k_scat2(
    const unsigned long long* __restrict__ part, const int* __restrict__ gcur,
    int* __restrict__ cursor, int* __restrict__ ssrc)
{
    const int w  = blockIdx.x & (SCAT_GROUPS - 1);
    const int g  = blockIdx.x >> 3;                 // 0..255 within group
    const int b0 = w * BUCKET_CAP;
    const int cnt = gcur[w] - b0;
    const int stride = (SCAT_BLOCKS / SCAT_GROUPS) * 256;   // 65536
    for (int i = g * 256 + threadIdx.x; i < cnt; i += stride) {
        unsigned long long e = part[b0 + i];
        int d = (int)(e >> 32);
        int s = (int)(e & 0xffffffffu);
        int p = atomicAdd(&cursor[d], 1);
        ssrc[p] = s;
    }
}

// ---------------- GEMM: out = relu?( concat(A0..A_{NC-1}) @ W + bias? ), row-scaled by dinv? --
template<int NC, bool RELU, bool BIAS, bool SCALE>
__global__ __launch_bounds__(256) void k_gemm(
    const unsigned short* __restrict__ A0, const unsigned short* __restrict__ A1,
    const unsigned short* __restrict__ A2, const unsigned short* __restrict__ WtG,
    const float* __restrict__ bias, const float* __restrict__ dinv,
    unsigned short* __restrict__ out)
{
    const int tid  = threadIdx.x;
    const int wave = tid >> 6, lane = tid & 63;
    const int l15 = lane & 15, lg = lane >> 4;
    const int K = NC * 128;
    const int rbase = blockIdx.x * 128 + wave * 32;

    f32x4 acc[2][8];
#pragma unroll
    for (int i = 0; i < 2; ++i)
#pragma unroll
        for (int j = 0; j < 8; ++j) acc[i][j] = (f32x4)(0.0f);

    int ar0 = rbase + l15;      if (ar0 >= N_NODES) ar0 = N_NODES - 1;
    int ar1 = rbase + 16 + l15; if (ar1 >= N_NODES) ar1 = N_NODES - 1;

    for (int c = 0; c < NC; ++c) {
        const unsigned short* Ac = (c == 0) ? A0 : ((c == 1) ? A1 : A2);
#pragma unroll
        for (int ks = 0; ks < 4; ++ks) {
            const int ko = ks * 32 + lg * 8;
            bf16x8 a0 = *(const bf16x8*)&Ac[(size_t)ar0 * 128 + ko];
            bf16x8 a1 = *(const bf16x8*)&Ac[(size_t)ar1 * 128 + ko];
#pragma unroll
            for (int cf = 0; cf < 8; ++cf) {
                bf16x8 b = *(const bf16x8*)&WtG[(size_t)(cf * 16 + l15) * K + c * 128 + ko];
                acc[0][cf] = __builtin_amdgcn_mfma_f32_16x16x32_bf16(a0, b, acc[0][cf], 0, 0, 0);
                acc[1][cf] = __builtin_amdgcn_mfma_f32_16x16x32_bf16(a1, b, acc[1][cf], 0, 0, 0);
            }
        }
    }
    float bvs[8];
#pragma unroll
    for (int cf = 0; cf < 8; ++cf) bvs[cf] = BIAS ? bias[cf * 16 + l15] : 0.0f;
#pragma unroll
    for (int ai = 0; ai < 2; ++ai) {
#pragma unroll
        for (int j = 0; j < 4; ++j) {
            int row = rbase + ai * 16 + lg * 4 + j;
            if (row < N_NODES) {
                float sc = SCALE ? dinv[row] : 1.0f;
#pragma unroll
                for (int cf = 0; cf < 8; ++cf) {
                    float v = acc[ai][cf][j] + bvs[cf];
                    if (RELU)  v = fmaxf(v, 0.0f);
                    if (SCALE) v *= sc;
                    out[(size_t)row * 128 + cf * 16 + l15] = f2b(v);
                }
            }
        }
    }
}

// ---------------- aggregation: out = relu(dinv_i * (sum t'_s + t'_i) + b), t' pre-scaled -----
template<bool FINAL>
__global__ __launch_bounds__(256) void k_agg(
    const unsigned short* __restrict__ t, const int* __restrict__ ssrc,
    const int* __restrict__ row_ptr, const int* __restrict__ deg,
    const float* __restrict__ dinv, const float* __restrict__ bias,
    void* __restrict__ out_v)
{
    const int wave = threadIdx.x >> 6;
    const int lane = threadIdx.x & 63;
    const int node = blockIdx.x * 4 + wave;
    if (node >= N_NODES) return;

    const int beg = row_ptr[node];
    const int cnt = deg[node] - 1;
    float a0 = 0.0f, a1 = 0.0f;

    for (int kb = 0; kb < cnt; kb += 64) {
        const int rem = cnt - kb;
        const int lim = rem < 64 ? rem : 64;
        int sk = 0;
        if (lane < lim) sk = ssrc[beg + kb + lane];

        int k = 0;
        for (; k + 8 <= lim; k += 8) {
            unsigned int p[8];
#pragma unroll
            for (int u = 0; u < 8; ++u) {
                int s = __builtin_amdgcn_readlane(sk, k + u);
                p[u] = *(const unsigned int*)&t[(size_t)s * 128 + lane * 2];
            }
#pragma unroll
            for (int u = 0; u < 8; ++u) {
                a0 += b2f((unsigned short)(p[u] & 0xffffu));
                a1 += b2f((unsigned short)(p[u] >> 16));
            }
        }
        for (; k < lim; ++k) {
            int s0 = __builtin_amdgcn_readlane(sk, k);
            unsigned int p0 = *(const unsigned int*)&t[(size_t)s0 * 128 + lane * 2];
            a0 += b2f((unsigned short)(p0 & 0xffffu));
            a1 += b2f((unsigned short)(p0 >> 16));
        }
    }

    // self-loop term is pre-scaled too: dinv_i^2 * t_i = dinv_i * t'_i
    unsigned int ps = *(const unsigned int*)&t[(size_t)node * 128 + lane * 2];
    a0 += b2f((unsigned short)(ps & 0xffffu));
    a1 += b2f((unsigned short)(ps >> 16));

    float di = dinv[node];
    f32x2 bv = *(const f32x2*)&bias[lane * 2];
    float o0 = fmaxf(di * a0 + bv[0], 0.0f);
    float o1 = fmaxf(di * a1 + bv[1], 0.0f);
    if (FINAL) {
        f32x2 po; po[0] = o0; po[1] = o1;
        *(f32x2*)((float*)out_v + (size_t)node * 128 + lane * 2) = po;
    } else {
        unsigned short* out = (unsigned short*)out_v;
        unsigned int po = (unsigned int)f2b(o0) | ((unsigned int)f2b(o1) << 16);
        *(unsigned int*)&out[(size_t)node * 128 + lane * 2] = po;
    }
}

// ---------------- launch ----------------
extern "C" void kernel_launch(void* const* d_in, const int* in_sizes, int n_in,
                              void* d_out, int out_size, void* d_ws, size_t ws_size,
                              hipStream_t stream)
{
    const float* x  = (const float*)d_in[0];
    const int*   ei = (const int*)d_in[1];
    const float* pW = (const float*)d_in[2];
    const float* pb = (const float*)d_in[3];
    const float* W1 = (const float*)d_in[4];
    const float* b1 = (const float*)d_in[5];
    const float* W2 = (const float*)d_in[6];
    const float* b2 = (const float*)d_in[7];
    const float* W3 = (const float*)d_in[8];
    const float* b3 = (const float*)d_in[9];
    const int* src = ei;
    const int* dst = ei + N_EDGES;

    char* ws = (char*)d_ws;
    size_t off = 0;
    auto alloc = [&](size_t bytes) -> char* {
        char* p = ws + off; off += (bytes + 255) & ~(size_t)255; return p;
    };
    const size_t NB = (size_t)N_NODES * 128;
    unsigned short* xb = (unsigned short*)alloc(NB * 2);
    unsigned short* xp = (unsigned short*)alloc(NB * 2);
    unsigned short* h1 = (unsigned short*)alloc(NB * 2);
    unsigned short* h2 = (unsigned short*)alloc(NB * 2);
    unsigned short* tb = (unsigned short*)alloc(NB * 2);   // GEMM temp; aliased as `part` during build
    unsigned short* Wb = (unsigned short*)alloc((size_t)114688 * 2);   // W^T bf16
    int*   deg  = (int*)alloc((size_t)N_NODES * 4);
    int*   rp   = (int*)alloc((size_t)N_NODES * 4);
    int*   cur  = (int*)alloc((size_t)N_NODES * 4);
    float* dinv = (float*)alloc((size_t)N_NODES * 4);
    int*   psum = (int*)alloc((size_t)SCAN_BLOCKS * 4);
    int*   poff = (int*)alloc((size_t)SCAN_BLOCKS * 4);
    int*   gcur = (int*)alloc((size_t)SCAT_GROUPS * 4);
    int*   ssrc = (int*)alloc((size_t)(N_EDGES + N_NODES) * 4);

    unsigned long long* part = (unsigned long long*)tb;   // 13.1 MB alias, dead before first tb write

    unsigned short* pWt = Wb;
    unsigned short* W1t = Wb + 16384;
    unsigned short* W2t = Wb + 32768;
    unsigned short* W3t = Wb + 65536;

    // casts
    k_cast4<<<(int)(NB / 4 + 255) / 256, 256, 0, stream>>>(x, xb, (int)(NB / 4));
    k_castWT<<<(114688 + 255) / 256, 256, 0, stream>>>(pW, W1, W2, W3, Wb);

    // graph build
    k_init_deg<<<(N_NODES + 255) / 256, 256, 0, stream>>>(deg, gcur);
    k_part<<<PART_BLOCKS, 256, 0, stream>>>(src, dst, gcur, part);
    k_hist2<<<HIST_BLOCKS, 256, 0, stream>>>(part, gcur, deg);
    k_deg_part<<<SCAN_BLOCKS, 256, 0, stream>>>(deg, psum);
    k_scan_off<<<1, 64, 0, stream>>>(psum, poff);
    k_scan_final<<<SCAN_BLOCKS, 256, 0, stream>>>(deg, poff, rp, cur, dinv);
    k_scat2<<<SCAT_BLOCKS, 256, 0, stream>>>(part, gcur, cur, ssrc);

    const int gblocks = (N_NODES + 127) / 128;
    const int ablocks = (N_NODES + 3) / 4;

    k_gemm<1, true,  true,  false><<<gblocks, 256, 0, stream>>>(xb, nullptr, nullptr, pWt, pb, dinv, xp);
    k_gemm<1, false, false, true ><<<gblocks, 256, 0, stream>>>(xb, nullptr, nullptr, W1t, nullptr, dinv, tb);
    k_agg<false><<<ablocks, 256, 0, stream>>>(tb, ssrc, rp, deg, dinv, b1, h1);
    k_gemm<2, false, false, true ><<<gblocks, 256, 0, stream>>>(xp, h1, nullptr, W2t, nullptr, dinv, tb);
    k_agg<false><<<ablocks, 256, 0, stream>>>(tb, ssrc, rp, deg, dinv, b2, h2);
    k_gemm<3, false, false, true ><<<gblocks, 256, 0, stream>>>(xp, h1, h2, W3t, nullptr, dinv, tb);
    k_agg<true><<<ablocks, 256, 0, stream>>>(tb, ssrc, rp, deg, dinv, b3, d_out);
}

// Round 11
// 548.272 us; speedup vs baseline: 1.1888x; 1.1840x over previous
//
#include <hip/hip_runtime.h>

#define N_NODES 100000
#define N_EDGES 1600000

typedef __attribute__((ext_vector_type(8))) short bf16x8;
typedef __attribute__((ext_vector_type(4))) float f32x4;
typedef __attribute__((ext_vector_type(2))) float f32x2;
typedef __attribute__((ext_vector_type(4))) unsigned short u16x4;

__device__ __forceinline__ float b2f(unsigned short u) {
    union { unsigned int i; float f; } v; v.i = ((unsigned int)u) << 16; return v.f;
}
__device__ __forceinline__ unsigned short f2b(float f) {
    union { float ff; unsigned int i; } v; v.ff = f;
    unsigned int x = v.i;
    x += 0x7fffu + ((x >> 16) & 1u);   // round-to-nearest-even
    return (unsigned short)(x >> 16);
}

// ---------------- f32 -> bf16 cast of x ----------------
__global__ __launch_bounds__(256) void k_cast4(const float* __restrict__ in,
                                               unsigned short* __restrict__ out, int n4) {
    int i = blockIdx.x * 256 + threadIdx.x;
    if (i < n4) {
        f32x4 v = *(const f32x4*)&in[(size_t)i * 4];
        u16x4 o;
        o[0] = f2b(v[0]); o[1] = f2b(v[1]); o[2] = f2b(v[2]); o[3] = f2b(v[3]);
        *(u16x4*)&out[(size_t)i * 4] = o;
    }
}

// cast + TRANSPOSE all 4 weight matrices -> Wt[col][k] bf16, contiguous pW|W1|W2|W3
__global__ __launch_bounds__(256) void k_castWT(
    const float* __restrict__ pW, const float* __restrict__ W1,
    const float* __restrict__ W2, const float* __restrict__ W3,
    unsigned short* __restrict__ out)
{
    int i = blockIdx.x * 256 + threadIdx.x;   // flat output index, 114688 total
    if (i >= 114688) return;
    const float* src; int K, base;
    if (i < 16384)      { src = pW; K = 128; base = 0; }
    else if (i < 32768) { src = W1; K = 128; base = 16384; }
    else if (i < 65536) { src = W2; K = 256; base = 32768; }
    else                { src = W3; K = 384; base = 65536; }
    int loc = i - base;
    int col = loc / K, k = loc - col * K;
    out[i] = f2b(src[(size_t)k * 128 + col]);
}

// ---------------- graph build ----------------
#define NB1 8                                        // level-1 buckets
#define WIN1 ((N_NODES + NB1 - 1) / NB1)             // 12500
#define CAP1 204800
#define PART_BLOCKS 782
#define PART_EPB 2048
#define SUBS 32                                      // sub-buckets per bucket
#define NWIN (NB1 * SUBS)                            // 256 windows
#define WIN2 ((WIN1 + SUBS - 1) / SUBS)              // 391
#define CAP2 8192                                    // mean 6250, +24 sigma
#define PART2_BLOCKS 2048

__global__ void k_init(int* gcur, int* gcur2) {
    int i = threadIdx.x;
    if (i < NB1)  gcur[i]  = i * CAP1;
    if (i < NWIN) gcur2[i] = i * CAP2;
}

// level-1: register-only edge partition into 8 dst-window buckets (coalesced writes)
__global__ __launch_bounds__(256) void k_part(
    const int* __restrict__ src, const int* __restrict__ dst,
    int* __restrict__ gcur, unsigned long long* __restrict__ part)
{
    __shared__ int bcnt[NB1];
    __shared__ int lcur[NB1];
    const int tid = threadIdx.x;
    const int ll  = tid & 63;
    const int base = blockIdx.x * PART_EPB;
    int sv[8], dv[8], bv[8];
    int mycnt[NB1] = {0, 0, 0, 0, 0, 0, 0, 0};
#pragma unroll
    for (int u = 0; u < 8; ++u) {
        int e = base + u * 256 + tid;
        bool val = e < N_EDGES;
        sv[u] = val ? src[e] : 0;
        dv[u] = val ? dst[e] : 0;
        bv[u] = val ? dv[u] / WIN1 : -1;
#pragma unroll
        for (int bk = 0; bk < NB1; ++bk) mycnt[bk] += (bv[u] == bk);
    }
    if (tid < NB1) bcnt[tid] = 0;
    __syncthreads();
#pragma unroll
    for (int bk = 0; bk < NB1; ++bk) {
        int c = mycnt[bk];
        for (int o = 1; o < 64; o <<= 1) c += __shfl_xor(c, o, 64);
        if (ll == 0 && c) atomicAdd(&bcnt[bk], c);
    }
    __syncthreads();
    if (tid < NB1) lcur[tid] = atomicAdd(&gcur[tid], bcnt[tid]);
    __syncthreads();
#pragma unroll
    for (int u = 0; u < 8; ++u) {
        unsigned long long masks[NB1]; int cnts[NB1];
#pragma unroll
        for (int bk = 0; bk < NB1; ++bk) {
            masks[bk] = __ballot(bv[u] == bk);
            cnts[bk]  = __popcll(masks[bk]);
        }
        int posv = 0;
        if (ll < NB1) posv = atomicAdd(&lcur[ll], cnts[ll]);
        int myoff = 0;
#pragma unroll
        for (int bk = 0; bk < NB1; ++bk) {
            int bb = __builtin_amdgcn_readlane(posv, bk);   // bk = compile-time constant lane
            if (bv[u] == bk) myoff = bb + __popcll(masks[bk] & ((1ULL << ll) - 1ULL));
        }
        if (bv[u] >= 0)
            part[myoff] = ((unsigned long long)(unsigned)dv[u] << 32) | (unsigned)sv[u];
    }
}

// level-2: bucket w -> 32 sub-buckets. 256 blocks per bucket, exclusive reservations.
// write-out via per-lane LDS atomicAdd (NO divergent readlane — that was R10's crash)
__global__ __launch_bounds__(256) void k_part2(
    const unsigned long long* __restrict__ part, const int* __restrict__ gcur,
    int* __restrict__ gcur2, unsigned long long* __restrict__ part2)
{
    __shared__ int bcnt[SUBS];
    __shared__ int lcur[SUBS];
    const int w   = blockIdx.x & (NB1 - 1);
    const int g   = blockIdx.x >> 3;                 // 0..255 within bucket
    const int tid = threadIdx.x;
    const int b0  = w * CAP1;
    const int cnt = gcur[w] - b0;
    const int chunk = (cnt + 255) >> 8;              // <= ~801
    const int lo = g * chunk;
    const int hi = min(lo + chunk, cnt);
    const int rounds = (hi > lo) ? ((hi - lo + 255) >> 8) : 0;   // <= 4
    const int nlo_base = w * WIN1;

    unsigned long long ev[4];
    int bkv[4];
    if (tid < SUBS) bcnt[tid] = 0;
    __syncthreads();
    for (int r = 0; r < rounds; ++r) {
        int i = lo + r * 256 + tid;
        bool val = i < hi;
        unsigned long long e = val ? part[b0 + i] : 0ULL;
        int bk = val ? ((int)(e >> 32) - nlo_base) / WIN2 : -1;
        ev[r] = e; bkv[r] = bk;
        if (val) atomicAdd(&bcnt[bk], 1);
    }
    __syncthreads();
    if (tid < SUBS) lcur[tid] = atomicAdd(&gcur2[w * SUBS + tid], bcnt[tid]);  // absolute base
    __syncthreads();
    for (int r = 0; r < rounds; ++r) {
        int mybk = bkv[r];
        if (mybk >= 0) {
            int off = atomicAdd(&lcur[mybk], 1);     // unique absolute slot, LDS atomic
            part2[off] = ev[r];
        }
    }
}

// one block per window: LDS degree hist (no device atomics), coalesced deg write
__global__ __launch_bounds__(512) void k_histw(
    const unsigned long long* __restrict__ part2, const int* __restrict__ gcur2,
    int* __restrict__ deg)
{
    __shared__ int cnt[WIN2];
    const int q = blockIdx.x;                        // 0..255
    const int w = q >> 5, s = q & (SUBS - 1);
    const int nlo = w * WIN1 + s * WIN2;
    const int nhi = w * WIN1 + min((s + 1) * WIN2, WIN1);
    const int wn = nhi - nlo;
    for (int i = threadIdx.x; i < wn; i += 512) cnt[i] = 0;
    __syncthreads();
    const int b0 = q * CAP2;
    const int ec = gcur2[q] - b0;
    for (int i = threadIdx.x; i < ec; i += 512) {
        int d = (int)(part2[b0 + i] >> 32);
        atomicAdd(&cnt[d - nlo], 1);
    }
    __syncthreads();
    for (int i = threadIdx.x; i < wn; i += 512) deg[nlo + i] = cnt[i] + 1;  // +1 self-loop
}

#define SCAN_CHUNK 2048
#define SCAN_BLOCKS ((N_NODES + SCAN_CHUNK - 1) / SCAN_CHUNK)   // 49

__global__ __launch_bounds__(256) void k_deg_part(const int* __restrict__ deg,
                                                  int* __restrict__ psum) {
    int b = blockIdx.x, t = threadIdx.x;
    int base = b * SCAN_CHUNK + t * 8;
    int s = 0;
#pragma unroll
    for (int i = 0; i < 8; ++i) { int idx = base + i; if (idx < N_NODES) s += deg[idx]; }
    for (int o = 1; o < 64; o <<= 1) s += __shfl_xor(s, o, 64);
    __shared__ int ws[4];
    if ((t & 63) == 0) ws[t >> 6] = s;
    __syncthreads();
    if (t == 0) psum[b] = ws[0] + ws[1] + ws[2] + ws[3];
}

__global__ void k_scan_off(const int* __restrict__ psum, int* __restrict__ poff) {
    int t = threadIdx.x;          // 64 threads
    int v = (t < SCAN_BLOCKS) ? psum[t] : 0;
    int sc = v;
    for (int o = 1; o < 64; o <<= 1) { int u = __shfl_up(sc, o, 64); if (t >= o) sc += u; }
    if (t < SCAN_BLOCKS) poff[t] = sc - v;
}

__global__ __launch_bounds__(256) void k_scan_final(
    const int* __restrict__ deg, const int* __restrict__ poff,
    int* __restrict__ row_ptr, float* __restrict__ dinv)
{
    int b = blockIdx.x, t = threadIdx.x;
    int base = b * SCAN_CHUNK + t * 8;
    int v[8]; int s = 0;
#pragma unroll
    for (int i = 0; i < 8; ++i) { int idx = base + i; v[i] = (idx < N_NODES) ? deg[idx] : 0; s += v[i]; }
    int lane = t & 63, wv = t >> 6;
    int sc = s;
    for (int o = 1; o < 64; o <<= 1) { int u = __shfl_up(sc, o, 64); if (lane >= o) sc += u; }
    __shared__ int wsum[4];
    if (lane == 63) wsum[wv] = sc;
    __syncthreads();
    int woff = 0;
    for (int i = 0; i < wv; ++i) woff += wsum[i];
    int excl = poff[b] + woff + sc - s;
#pragma unroll
    for (int i = 0; i < 8; ++i) {
        int idx = base + i;
        if (idx < N_NODES) {
            row_ptr[idx] = excl;
            dinv[idx] = rsqrtf((float)v[i]);
            excl += v[i];
        }
    }
}

// one block per window: LDS cursors (no device atomics), exclusive ssrc region
__global__ __launch_bounds__(512) void k_sortw(
    const unsigned long long* __restrict__ part2, const int* __restrict__ gcur2,
    const int* __restrict__ row_ptr, int* __restrict__ ssrc)
{
    __shared__ int cur[WIN2];
    const int q = blockIdx.x;
    const int w = q >> 5, s = q & (SUBS - 1);
    const int nlo = w * WIN1 + s * WIN2;
    const int nhi = w * WIN1 + min((s + 1) * WIN2, WIN1);
    const int wn = nhi - nlo;
    for (int i = threadIdx.x; i < wn; i += 512) cur[i] = row_ptr[nlo + i];
    __syncthreads();
    const int b0 = q * CAP2;
    const int ec = gcur2[q] - b0;
    for (int i = threadIdx.x; i < ec; i += 512) {
        unsigned long long e = part2[b0 + i];
        int d = (int)(e >> 32);
        int p = atomicAdd(&cur[d - nlo], 1);
        ssrc[p] = (int)(e & 0xffffffffu);
    }
}

// ---------------- GEMM: out = relu?( concat(A0..A_{NC-1}) @ W + bias? ), row-scaled by dinv? --
template<int NC, bool RELU, bool BIAS, bool SCALE>
__global__ __launch_bounds__(256) void k_gemm(
    const unsigned short* __restrict__ A0, const unsigned short* __restrict__ A1,
    const unsigned short* __restrict__ A2, const unsigned short* __restrict__ WtG,
    const float* __restrict__ bias, const float* __restrict__ dinv,
    unsigned short* __restrict__ out)
{
    const int tid  = threadIdx.x;
    const int wave = tid >> 6, lane = tid & 63;
    const int l15 = lane & 15, lg = lane >> 4;
    const int K = NC * 128;
    const int rbase = blockIdx.x * 128 + wave * 32;

    f32x4 acc[2][8];
#pragma unroll
    for (int i = 0; i < 2; ++i)
#pragma unroll
        for (int j = 0; j < 8; ++j) acc[i][j] = (f32x4)(0.0f);

    int ar0 = rbase + l15;      if (ar0 >= N_NODES) ar0 = N_NODES - 1;
    int ar1 = rbase + 16 + l15; if (ar1 >= N_NODES) ar1 = N_NODES - 1;

    for (int c = 0; c < NC; ++c) {
        const unsigned short* Ac = (c == 0) ? A0 : ((c == 1) ? A1 : A2);
#pragma unroll
        for (int ks = 0; ks < 4; ++ks) {
            const int ko = ks * 32 + lg * 8;
            bf16x8 a0 = *(const bf16x8*)&Ac[(size_t)ar0 * 128 + ko];
            bf16x8 a1 = *(const bf16x8*)&Ac[(size_t)ar1 * 128 + ko];
#pragma unroll
            for (int cf = 0; cf < 8; ++cf) {
                bf16x8 b = *(const bf16x8*)&WtG[(size_t)(cf * 16 + l15) * K + c * 128 + ko];
                acc[0][cf] = __builtin_amdgcn_mfma_f32_16x16x32_bf16(a0, b, acc[0][cf], 0, 0, 0);
                acc[1][cf] = __builtin_amdgcn_mfma_f32_16x16x32_bf16(a1, b, acc[1][cf], 0, 0, 0);
            }
        }
    }
    float bvs[8];
#pragma unroll
    for (int cf = 0; cf < 8; ++cf) bvs[cf] = BIAS ? bias[cf * 16 + l15] : 0.0f;
#pragma unroll
    for (int ai = 0; ai < 2; ++ai) {
#pragma unroll
        for (int j = 0; j < 4; ++j) {
            int row = rbase + ai * 16 + lg * 4 + j;
            if (row < N_NODES) {
                float sc = SCALE ? dinv[row] : 1.0f;
#pragma unroll
                for (int cf = 0; cf < 8; ++cf) {
                    float v = acc[ai][cf][j] + bvs[cf];
                    if (RELU)  v = fmaxf(v, 0.0f);
                    if (SCALE) v *= sc;
                    out[(size_t)row * 128 + cf * 16 + l15] = f2b(v);
                }
            }
        }
    }
}

// ---------------- aggregation: out = relu(dinv_i * (sum t'_s + t'_i) + b), t' pre-scaled -----
template<bool FINAL>
__global__ __launch_bounds__(256) void k_agg(
    const unsigned short* __restrict__ t, const int* __restrict__ ssrc,
    const int* __restrict__ row_ptr, const int* __restrict__ deg,
    const float* __restrict__ dinv, const float* __restrict__ bias,
    void* __restrict__ out_v)
{
    const int wave = threadIdx.x >> 6;
    const int lane = threadIdx.x & 63;
    const int node = blockIdx.x * 4 + wave;
    if (node >= N_NODES) return;

    const int beg = row_ptr[node];
    const int cnt = deg[node] - 1;
    float a0 = 0.0f, a1 = 0.0f;

    for (int kb = 0; kb < cnt; kb += 64) {
        const int rem = cnt - kb;
        const int lim = rem < 64 ? rem : 64;
        int sk = 0;
        if (lane < lim) sk = ssrc[beg + kb + lane];

        int k = 0;
        for (; k + 8 <= lim; k += 8) {
            unsigned int p[8];
#pragma unroll
            for (int u = 0; u < 8; ++u) {
                int s = __builtin_amdgcn_readlane(sk, k + u);   // k+u wave-uniform
                p[u] = *(const unsigned int*)&t[(size_t)s * 128 + lane * 2];
            }
#pragma unroll
            for (int u = 0; u < 8; ++u) {
                a0 += b2f((unsigned short)(p[u] & 0xffffu));
                a1 += b2f((unsigned short)(p[u] >> 16));
            }
        }
        for (; k < lim; ++k) {
            int s0 = __builtin_amdgcn_readlane(sk, k);
            unsigned int p0 = *(const unsigned int*)&t[(size_t)s0 * 128 + lane * 2];
            a0 += b2f((unsigned short)(p0 & 0xffffu));
            a1 += b2f((unsigned short)(p0 >> 16));
        }
    }

    // self-loop term pre-scaled: dinv_i^2 * t_i = dinv_i * t'_i
    unsigned int ps = *(const unsigned int*)&t[(size_t)node * 128 + lane * 2];
    a0 += b2f((unsigned short)(ps & 0xffffu));
    a1 += b2f((unsigned short)(ps >> 16));

    float di = dinv[node];
    f32x2 bv = *(const f32x2*)&bias[lane * 2];
    float o0 = fmaxf(di * a0 + bv[0], 0.0f);
    float o1 = fmaxf(di * a1 + bv[1], 0.0f);
    if (FINAL) {
        f32x2 po; po[0] = o0; po[1] = o1;
        *(f32x2*)((float*)out_v + (size_t)node * 128 + lane * 2) = po;
    } else {
        unsigned short* out = (unsigned short*)out_v;
        unsigned int po = (unsigned int)f2b(o0) | ((unsigned int)f2b(o1) << 16);
        *(unsigned int*)&out[(size_t)node * 128 + lane * 2] = po;
    }
}

// ---------------- launch ----------------
extern "C" void kernel_launch(void* const* d_in, const int* in_sizes, int n_in,
                              void* d_out, int out_size, void* d_ws, size_t ws_size,
                              hipStream_t stream)
{
    const float* x  = (const float*)d_in[0];
    const int*   ei = (const int*)d_in[1];
    const float* pW = (const float*)d_in[2];
    const float* pb = (const float*)d_in[3];
    const float* W1 = (const float*)d_in[4];
    const float* b1 = (const float*)d_in[5];
    const float* W2 = (const float*)d_in[6];
    const float* b2 = (const float*)d_in[7];
    const float* W3 = (const float*)d_in[8];
    const float* b3 = (const float*)d_in[9];
    const int* src = ei;
    const int* dst = ei + N_EDGES;

    char* ws = (char*)d_ws;
    size_t off = 0;
    auto alloc = [&](size_t bytes) -> char* {
        char* p = ws + off; off += (bytes + 255) & ~(size_t)255; return p;
    };
    const size_t NB = (size_t)N_NODES * 128;
    unsigned short* xb = (unsigned short*)alloc(NB * 2);
    unsigned short* xp = (unsigned short*)alloc(NB * 2);
    unsigned short* h1 = (unsigned short*)alloc(NB * 2);
    unsigned short* h2 = (unsigned short*)alloc(NB * 2);   // part2 (16.8 MB) aliases here during build
    unsigned short* tb = (unsigned short*)alloc(NB * 2);   // part  (13.1 MB) aliases here during build
    unsigned short* Wb = (unsigned short*)alloc((size_t)114688 * 2);   // W^T bf16
    int*   deg  = (int*)alloc((size_t)N_NODES * 4);
    int*   rp   = (int*)alloc((size_t)N_NODES * 4);
    float* dinv = (float*)alloc((size_t)N_NODES * 4);
    int*   psum = (int*)alloc((size_t)SCAN_BLOCKS * 4);
    int*   poff = (int*)alloc((size_t)SCAN_BLOCKS * 4);
    int*   gcur = (int*)alloc((size_t)NB1 * 4);
    int*   gcur2= (int*)alloc((size_t)NWIN * 4);
    int*   ssrc = (int*)alloc((size_t)(N_EDGES + N_NODES) * 4);

    // aliases: consumed strictly before their hosts' first write (same stream)
    unsigned long long* part  = (unsigned long long*)tb;   // dead before gemm writes tb
    unsigned long long* part2 = (unsigned long long*)h2;   // dead before agg writes h2

    unsigned short* pWt = Wb;
    unsigned short* W1t = Wb + 16384;
    unsigned short* W2t = Wb + 32768;
    unsigned short* W3t = Wb + 65536;

    // casts
    k_cast4<<<(int)(NB / 4 + 255) / 256, 256, 0, stream>>>(x, xb, (int)(NB / 4));
    k_castWT<<<(114688 + 255) / 256, 256, 0, stream>>>(pW, W1, W2, W3, Wb);

    // graph build (no per-edge device atomics anywhere)
    k_init<<<1, 512, 0, stream>>>(gcur, gcur2);
    k_part<<<PART_BLOCKS, 256, 0, stream>>>(src, dst, gcur, part);
    k_part2<<<PART2_BLOCKS, 256, 0, stream>>>(part, gcur, gcur2, part2);
    k_histw<<<NWIN, 512, 0, stream>>>(part2, gcur2, deg);
    k_deg_part<<<SCAN_BLOCKS, 256, 0, stream>>>(deg, psum);
    k_scan_off<<<1, 64, 0, stream>>>(psum, poff);
    k_scan_final<<<SCAN_BLOCKS, 256, 0, stream>>>(deg, poff, rp, dinv);
    k_sortw<<<NWIN, 512, 0, stream>>>(part2, gcur2, rp, ssrc);

    const int gblocks = (N_NODES + 127) / 128;
    const int ablocks = (N_NODES + 3) / 4;

    k_gemm<1, true,  true,  false><<<gblocks, 256, 0, stream>>>(xb, nullptr, nullptr, pWt, pb, dinv, xp);
    k_gemm<1, false, false, true ><<<gblocks, 256, 0, stream>>>(xb, nullptr, nullptr, W1t, nullptr, dinv, tb);
    k_agg<false><<<ablocks, 256, 0, stream>>>(tb, ssrc, rp, deg, dinv, b1, h1);
    k_gemm<2, false, false, true ><<<gblocks, 256, 0, stream>>>(xp, h1, nullptr, W2t, nullptr, dinv, tb);
    k_agg<false><<<ablocks, 256, 0, stream>>>(tb, ssrc, rp, deg, dinv, b2, h2);
    k_gemm<3, false, false, true ><<<gblocks, 256, 0, stream>>>(xp, h1, h2, W3t, nullptr, dinv, tb);
    k_agg<true><<<ablocks, 256, 0, stream>>>(tb, ssrc, rp, deg, dinv, b3, d_out);
}